// Round 3
// baseline (63.650 us; speedup 1.0000x reference)
//
#include <hip/hip_runtime.h>

// Time_Pos_Encoding: out[b,s,d] = x[b,s,d] + pe[s,d]
//   rdiv   = 10000^(-2d/D)
//   pe even d: sin(s*rdiv) + sin(101*rdiv)
//   pe odd  d: cos(s*rdiv) + cos(101*rdiv)
// Shapes fixed by the reference: B=8, S=4096, D=1024, f32.
//
// R2 -> R3: __builtin_nontemporal_store needs a native vector type, not HIP's
// float4 class. Use ext_vector_type(4). Logic unchanged from R2:
//  * all 8 batch loads issued into a register block first (ILP hides latency)
//  * non-temporal stores keep out (128 MiB) from evicting x (128 MiB) in the
//    256 MiB LLC -> x stays L3-resident across replays, FETCH_SIZE -> ~0

typedef float f32x4 __attribute__((ext_vector_type(4)));

#define TWO_PI   6.283185307179586f
#define INV_2PI  0.15915494309189535f

// __sinf/__cosf map to v_sin/v_cos (input in revolutions, limited domain);
// pre-reduce radians to [-pi, pi] so the fast path is valid for ang up to 4095.
__device__ __forceinline__ float fast_sin(float a) {
    float k = rintf(a * INV_2PI);
    float r = fmaf(-k, TWO_PI, a);
    return __sinf(r);
}
__device__ __forceinline__ float fast_cos(float a) {
    float k = rintf(a * INV_2PI);
    float r = fmaf(-k, TWO_PI, a);
    return __cosf(r);
}

__global__ __launch_bounds__(256) void tpe_kernel(const float* __restrict__ x,
                                                  float* __restrict__ out) {
    constexpr int S = 4096;
    constexpr int D = 1024;
    constexpr int B = 8;

    const int s  = blockIdx.x;            // one block per sequence row
    const int d0 = threadIdx.x * 4;       // 4 consecutive d per thread

    const size_t base = (size_t)s * D + (size_t)d0;
    constexpr size_t bstride = (size_t)S * (size_t)D;

    // Issue ALL batch loads first -> 8 outstanding global_load_dwordx4/thread.
    f32x4 v[8];
#pragma unroll
    for (int b = 0; b < B; ++b)
        v[b] = __builtin_nontemporal_load(
            reinterpret_cast<const f32x4*>(x + base + (size_t)b * bstride));

    // Compute pe while the loads are in flight.
    constexpr float C = 13.287712379549449f * 2.0f / (float)D;  // 2*log2(10000)/D
    const float pos = (float)s;
    float pe[4];
#pragma unroll
    for (int j = 0; j < 4; ++j) {
        const int d = d0 + j;
        const float rdiv = exp2f(-C * (float)d);   // 10000^(-2d/D)
        const float ap = pos * rdiv;
        const float at = 101.0f * rdiv;            // TIME_STEP = 101
        if ((d & 1) == 0)
            pe[j] = fast_sin(ap) + fast_sin(at);
        else
            pe[j] = fast_cos(ap) + fast_cos(at);
    }

#pragma unroll
    for (int b = 0; b < B; ++b) {
        f32x4 ov;
        ov.x = v[b].x + pe[0];
        ov.y = v[b].y + pe[1];
        ov.z = v[b].z + pe[2];
        ov.w = v[b].w + pe[3];
        // nt store: don't let out's write-allocate evict x from the LLC
        __builtin_nontemporal_store(
            ov, reinterpret_cast<f32x4*>(out + base + (size_t)b * bstride));
    }
}

extern "C" void kernel_launch(void* const* d_in, const int* in_sizes, int n_in,
                              void* d_out, int out_size, void* d_ws, size_t ws_size,
                              hipStream_t stream) {
    const float* x = (const float*)d_in[0];
    float* out = (float*)d_out;
    // S=4096 blocks x 256 threads; each thread: 4 d's x 8 batches = 32 elems
    tpe_kernel<<<4096, 256, 0, stream>>>(x, out);
}

// Round 4
// 48.774 us; speedup vs baseline: 1.3050x; 1.3050x over previous
//
#include <hip/hip_runtime.h>

// Time_Pos_Encoding: out[b,s,d] = x[b,s,d] + pe[s,d]
//   rdiv   = 10000^(-2d/D)
//   pe even d: sin(s*rdiv) + sin(101*rdiv)
//   pe odd  d: cos(s*rdiv) + cos(101*rdiv)
// Shapes fixed by the reference: B=8, S=4096, D=1024, f32.
//
// R3 -> R4: R3's nontemporal LOADS were the regression (bypassed LLC, x
// re-fetched from HBM every replay). Loads back to default (cached);
// nt hint kept on STORES only, so out's write-allocate doesn't evict x
// from the 256 MiB LLC.

typedef float f32x4 __attribute__((ext_vector_type(4)));

#define TWO_PI   6.283185307179586f
#define INV_2PI  0.15915494309189535f

// __sinf/__cosf map to v_sin/v_cos (input in revolutions, limited domain);
// pre-reduce radians to [-pi, pi] so the fast path is valid for ang up to 4095.
__device__ __forceinline__ float fast_sin(float a) {
    float k = rintf(a * INV_2PI);
    float r = fmaf(-k, TWO_PI, a);
    return __sinf(r);
}
__device__ __forceinline__ float fast_cos(float a) {
    float k = rintf(a * INV_2PI);
    float r = fmaf(-k, TWO_PI, a);
    return __cosf(r);
}

__global__ __launch_bounds__(256) void tpe_kernel(const float* __restrict__ x,
                                                  float* __restrict__ out) {
    constexpr int S = 4096;
    constexpr int D = 1024;
    constexpr int B = 8;

    const int s  = blockIdx.x;            // one block per sequence row
    const int d0 = threadIdx.x * 4;       // 4 consecutive d per thread

    const size_t base = (size_t)s * D + (size_t)d0;
    constexpr size_t bstride = (size_t)S * (size_t)D;

    // Issue ALL batch loads first -> 8 outstanding global_load_dwordx4/thread.
    // Default (cached) loads: x should become LLC-resident across replays.
    f32x4 v[8];
#pragma unroll
    for (int b = 0; b < B; ++b)
        v[b] = *reinterpret_cast<const f32x4*>(x + base + (size_t)b * bstride);

    // Compute pe while the loads are in flight.
    constexpr float C = 13.287712379549449f * 2.0f / (float)D;  // 2*log2(10000)/D
    const float pos = (float)s;
    float pe[4];
#pragma unroll
    for (int j = 0; j < 4; ++j) {
        const int d = d0 + j;
        const float rdiv = exp2f(-C * (float)d);   // 10000^(-2d/D)
        const float ap = pos * rdiv;
        const float at = 101.0f * rdiv;            // TIME_STEP = 101
        if ((d & 1) == 0)
            pe[j] = fast_sin(ap) + fast_sin(at);
        else
            pe[j] = fast_cos(ap) + fast_cos(at);
    }

#pragma unroll
    for (int b = 0; b < B; ++b) {
        f32x4 ov;
        ov.x = v[b].x + pe[0];
        ov.y = v[b].y + pe[1];
        ov.z = v[b].z + pe[2];
        ov.w = v[b].w + pe[3];
        // nt STORE only: don't let out's write-allocate evict x from the LLC
        __builtin_nontemporal_store(
            ov, reinterpret_cast<f32x4*>(out + base + (size_t)b * bstride));
    }
}

extern "C" void kernel_launch(void* const* d_in, const int* in_sizes, int n_in,
                              void* d_out, int out_size, void* d_ws, size_t ws_size,
                              hipStream_t stream) {
    const float* x = (const float*)d_in[0];
    float* out = (float*)d_out;
    // S=4096 blocks x 256 threads; each thread: 4 d's x 8 batches = 32 elems
    tpe_kernel<<<4096, 256, 0, stream>>>(x, out);
}

// Round 5
// 44.146 us; speedup vs baseline: 1.4418x; 1.1048x over previous
//
#include <hip/hip_runtime.h>

// Time_Pos_Encoding: out[b,s,d] = x[b,s,d] + pe[s,d]
//   rdiv = 10000^(-2d/D); even d: sin(s*rdiv)+sin(101*rdiv); odd: cos+cos
// B=8, S=4096, D=1024, f32.
//
// R4 -> R5: flat contiguous streaming. Block = 8 CONSECUTIVE flat rows
// (one 32 KB span), matching the m13 copy benchmark's access shape, instead
// of 8 rows strided 16 MiB apart. 4096 % 8 == 0 so a block's rows share the
// batch and have consecutive s -> pe carried across rows by a 2-FMA rotation
// (angle-addition) from one exact range-reduced base evaluation.
// nt store dropped (R4 proved it has no effect on FETCH_SIZE or dur).

typedef float f32x4 __attribute__((ext_vector_type(4)));

#define TWO_PI   6.283185307179586f
#define INV_2PI  0.15915494309189535f

// v_sin/v_cos need pre-reduced input; reduce radians to [-pi, pi].
__device__ __forceinline__ float fast_sin(float a) {
    float k = rintf(a * INV_2PI);
    return __sinf(fmaf(-k, TWO_PI, a));
}
__device__ __forceinline__ float fast_cos(float a) {
    float k = rintf(a * INV_2PI);
    return __cosf(fmaf(-k, TWO_PI, a));
}

__global__ __launch_bounds__(256) void tpe_kernel(const float* __restrict__ x,
                                                  float* __restrict__ out) {
    constexpr int D    = 1024;
    constexpr int ROWS = 8;   // consecutive flat rows per block = 32 KB span

    const int tid = threadIdx.x;
    const long long row0 = (long long)blockIdx.x * ROWS;  // flat row in [0, 32768)
    const int s0 = (int)(row0 & 4095);   // all ROWS rows: same batch, s consecutive
    const int d0 = tid * 4;

    const float* xp = x   + row0 * D + d0;
    float*       op = out + row0 * D + d0;

    // 8 independent contiguous loads first (ILP; block covers 32 KB linearly)
    f32x4 v[ROWS];
#pragma unroll
    for (int r = 0; r < ROWS; ++r)
        v[r] = *reinterpret_cast<const f32x4*>(xp + (size_t)r * D);

    // pe state for row s0, carried by rotation for rows s0+1..s0+7
    constexpr float C = 2.0f * 13.287712379549449f / (float)D;  // 2*log2(10000)/D
    float sp[4], cp[4], sr[4], cr[4], tterm[4];
#pragma unroll
    for (int j = 0; j < 4; ++j) {
        const float rdiv = exp2f(-C * (float)(d0 + j));  // 10000^(-2d/D), <= 1
        const float ap = (float)s0 * rdiv;
        sp[j] = fast_sin(ap);
        cp[j] = fast_cos(ap);
        sr[j] = __sinf(rdiv);            // rdiv in (0,1] rad: no reduction needed
        cr[j] = __cosf(rdiv);
        const float at = 101.0f * rdiv;  // TIME_STEP = 101
        tterm[j] = ((j & 1) == 0) ? fast_sin(at) : fast_cos(at);
    }

#pragma unroll
    for (int r = 0; r < ROWS; ++r) {
        f32x4 ov;
        ov.x = v[r].x + sp[0] + tterm[0];   // d0+0 even -> sin
        ov.y = v[r].y + cp[1] + tterm[1];   // d0+1 odd  -> cos
        ov.z = v[r].z + sp[2] + tterm[2];
        ov.w = v[r].w + cp[3] + tterm[3];
        *reinterpret_cast<f32x4*>(op + (size_t)r * D) = ov;

        // rotate (sin,cos) of s*rdiv by rdiv -> next row's angle
#pragma unroll
        for (int j = 0; j < 4; ++j) {
            const float ns = fmaf(sp[j], cr[j],  cp[j] * sr[j]);
            const float nc = fmaf(cp[j], cr[j], -sp[j] * sr[j]);
            sp[j] = ns; cp[j] = nc;
        }
    }
}

extern "C" void kernel_launch(void* const* d_in, const int* in_sizes, int n_in,
                              void* d_out, int out_size, void* d_ws, size_t ws_size,
                              hipStream_t stream) {
    const float* x = (const float*)d_in[0];
    float* out = (float*)d_out;
    // 32768 flat rows / 8 rows-per-block = 4096 blocks x 256 threads
    tpe_kernel<<<4096, 256, 0, stream>>>(x, out);
}